// Round 8
// baseline (253.763 us; speedup 1.0000x reference)
//
#include <hip/hip_runtime.h>
#include <math.h>

#define TEMP_INV (1.0f / 0.07f)
#define WEIGHT 0.5f
#define EPS 1e-8f
#define BB 64
#define TT 512
#define DD 512
#define RR 8   // rows per wave in sims_kernel (R2-proven best)
#define SIMS_BLOCKS ((TT / (4 * RR)) * BB * 2)   // 16*64*2 = 2048

__device__ inline float wave_sum(float v) {
    for (int o = 32; o >= 1; o >>= 1) v += __shfl_xor(v, o, 64);
    return v;
}
__device__ inline int wave_max_i(int v) {
    for (int o = 32; o >= 1; o >>= 1) v = max(v, __shfl_xor(v, o, 64));
    return v;
}
__device__ inline int wave_min_i(int v) {
    for (int o = 32; o >= 1; o >>= 1) v = min(v, __shfl_xor(v, o, 64));
    return v;
}

// One block (256 threads) per batch element b:
//  - argmax(mask[b,:]) with first-occurrence semantics
//  - normalized anchors a_anchor[b,:], v_anchor[b,:]
//  - pos[b] = dot(v_anchor_n, a_anchor_n)/TEMP
//  - zero the neg accumulators + ticket counter (ws is poisoned each call)
__global__ __launch_bounds__(256) void prep_kernel(
    const float* __restrict__ video, const float* __restrict__ audio,
    const int* __restrict__ mask,
    float* __restrict__ a_anchor, float* __restrict__ v_anchor,
    float* __restrict__ pos, float* __restrict__ neg, int* __restrict__ idx_out,
    int* __restrict__ cnt)
{
    const int b = blockIdx.x;
    const int tid = threadIdx.x;
    const int wid = tid >> 6, lane = tid & 63;
    __shared__ int sh_i[4];
    __shared__ float sh_f[4][3];
    __shared__ int s_idx;
    __shared__ float s_inva, s_invv;

    // ---- argmax (first max) over mask[b, 0..T) ----
    int m0 = mask[b * TT + tid];
    int m1 = mask[b * TT + tid + 256];
    int vmax = wave_max_i(max(m0, m1));
    if (lane == 0) sh_i[wid] = vmax;
    __syncthreads();
    if (tid == 0) {
        int r = sh_i[0];
        for (int i = 1; i < 4; i++) r = max(r, sh_i[i]);
        sh_i[0] = r;
    }
    __syncthreads();
    vmax = sh_i[0];
    __syncthreads();
    int cand = (m0 == vmax) ? tid : 0x7fffffff;
    int cand1 = (m1 == vmax) ? (tid + 256) : 0x7fffffff;
    cand = min(cand, cand1);
    cand = wave_min_i(cand);
    if (lane == 0) sh_i[wid] = cand;
    __syncthreads();
    if (tid == 0) {
        int r = sh_i[0];
        for (int i = 1; i < 4; i++) r = min(r, sh_i[i]);
        s_idx = r;
    }
    __syncthreads();
    const int idx = s_idx;

    // ---- anchor rows: sumsq(audio), sumsq(video), dot(audio,video) ----
    const float* arow = audio + ((size_t)(b * TT + idx)) * DD;
    const float* vrow = video + ((size_t)(b * TT + idx)) * DD;
    float a0 = arow[tid], a1 = arow[tid + 256];
    float v0 = vrow[tid], v1 = vrow[tid + 256];
    float ssa = a0 * a0 + a1 * a1;
    float ssv = v0 * v0 + v1 * v1;
    float dav = a0 * v0 + a1 * v1;
    ssa = wave_sum(ssa);
    ssv = wave_sum(ssv);
    dav = wave_sum(dav);
    if (lane == 0) { sh_f[wid][0] = ssa; sh_f[wid][1] = ssv; sh_f[wid][2] = dav; }
    __syncthreads();
    if (tid == 0) {
        float ra = 0.f, rv = 0.f, rd = 0.f;
        for (int i = 0; i < 4; i++) { ra += sh_f[i][0]; rv += sh_f[i][1]; rd += sh_f[i][2]; }
        float inva = 1.0f / fmaxf(sqrtf(ra), EPS);
        float invv = 1.0f / fmaxf(sqrtf(rv), EPS);
        s_inva = inva; s_invv = invv;
        pos[b] = rd * inva * invv * TEMP_INV;
        neg[b] = 0.0f;
        neg[BB + b] = 0.0f;
        idx_out[b] = idx;
        *cnt = 0;   // all 64 blocks write 0 — benign same-value race
    }
    __syncthreads();
    const float inva = s_inva, invv = s_invv;
    a_anchor[b * DD + tid] = a0 * inva;
    a_anchor[b * DD + tid + 256] = a1 * inva;
    v_anchor[b * DD + tid] = v0 * invv;
    v_anchor[b * DD + tid + 256] = v1 * invv;
}

// grid (T/32, B, 2); 256-thread blocks, one wave per RR=8 consecutive rows.
// EXACT R2 load/compute body (plain C loads, compiler-scheduled pipeline —
// every full-drain variant [sched_barrier / LDS-DMA / asm vmcnt(0)] landed
// at ~100 us vs this structure's 61.8 us; do NOT force drains or MLP).
// Finalize is fused via a no-spin last-block ticket: saves one launch gap.
__global__ __launch_bounds__(256) void sims_kernel(
    const float* __restrict__ video, const float* __restrict__ audio,
    const float* __restrict__ a_anchor, const float* __restrict__ v_anchor,
    const int* __restrict__ idx_arr, float* __restrict__ neg,
    const float* __restrict__ pos, int* __restrict__ cnt,
    float* __restrict__ out)
{
    const int b = blockIdx.y;
    const int dir = blockIdx.z;
    const int tid = threadIdx.x;
    const int wid = tid >> 6, lane = tid & 63;
    const int t0 = blockIdx.x * (4 * RR) + wid * RR;

    const float* base = (dir == 0 ? video : audio) + (size_t)b * TT * DD;
    const float* anc = (dir == 0 ? a_anchor : v_anchor) + b * DD;

    // anchor first: L2-hit, completes early
    float4 c0 = *(const float4*)(anc + lane * 4);
    float4 c1 = *(const float4*)(anc + 256 + lane * 4);

    float4 r0[RR], r1[RR];
#pragma unroll
    for (int r = 0; r < RR; r++) {
        const float* row = base + (size_t)(t0 + r) * DD;
        r0[r] = *(const float4*)(row + lane * 4);
        r1[r] = *(const float4*)(row + 256 + lane * 4);
    }

    float dot[RR], nrm[RR];
#pragma unroll
    for (int r = 0; r < RR; r++) {
        dot[r] = r0[r].x * c0.x + r0[r].y * c0.y + r0[r].z * c0.z + r0[r].w * c0.w
               + r1[r].x * c1.x + r1[r].y * c1.y + r1[r].z * c1.z + r1[r].w * c1.w;
        nrm[r] = r0[r].x * r0[r].x + r0[r].y * r0[r].y + r0[r].z * r0[r].z + r0[r].w * r0[r].w
               + r1[r].x * r1[r].x + r1[r].y * r1[r].y + r1[r].z * r1[r].z + r1[r].w * r1[r].w;
    }

    // batched butterfly: 6 levels, 2*RR independent shfl-adds per level
#pragma unroll
    for (int o = 32; o >= 1; o >>= 1) {
#pragma unroll
        for (int r = 0; r < RR; r++) {
            dot[r] += __shfl_xor(dot[r], o, 64);
            nrm[r] += __shfl_xor(nrm[r], o, 64);
        }
    }

    if (lane == 0) {
        const int idx = idx_arr[b];
        float local = 0.0f;
#pragma unroll
        for (int r = 0; r < RR; r++) {
            const int t = t0 + r;
            float sim = dot[r] / fmaxf(sqrtf(nrm[r]), EPS) * TEMP_INV;
            local += (t == idx) ? 0.0f : expf(sim);
        }
        atomicAdd(&neg[dir * BB + b], local);
    }

    // ---- fused finalize: no-spin last-block ticket ----
    __syncthreads();              // all waves' neg atomicAdds issued
    __shared__ int s_last;
    if (tid == 0) {
        __threadfence();          // neg add globally visible before ticket
        int old = atomicAdd(cnt, 1);
        s_last = (old == SIMS_BLOCKS - 1) ? 1 : 0;
    }
    __syncthreads();
    if (s_last && tid < 64) {
        __threadfence();
        const int bb = tid;       // one wave finalizes all 64 batches
        // device-scope atomic reads — per-XCD L2s are not coherent (G16)
        float na = atomicAdd(&neg[bb], 0.0f);
        float nv = atomicAdd(&neg[BB + bb], 0.0f);
        float term = WEIGHT * (logf(na) + logf(nv)) - pos[bb];
        term = wave_sum(term);
        if (bb == 0) out[0] = term / (float)BB;
    }
}

extern "C" void kernel_launch(void* const* d_in, const int* in_sizes, int n_in,
                              void* d_out, int out_size, void* d_ws, size_t ws_size,
                              hipStream_t stream)
{
    const float* video = (const float*)d_in[0];
    const float* audio = (const float*)d_in[1];
    const int* mask = (const int*)d_in[2];

    float* ws = (float*)d_ws;
    float* a_anchor = ws;                 // B*D
    float* v_anchor = ws + BB * DD;       // B*D
    float* pos = ws + 2 * BB * DD;        // B
    float* neg = pos + BB;                // 2*B
    int* idx = (int*)(neg + 2 * BB);      // B
    int* cnt = idx + BB;                  // 1

    prep_kernel<<<BB, 256, 0, stream>>>(video, audio, mask, a_anchor, v_anchor,
                                        pos, neg, idx, cnt);
    dim3 grid(TT / (4 * RR), BB, 2);
    sims_kernel<<<grid, 256, 0, stream>>>(video, audio, a_anchor, v_anchor,
                                          idx, neg, pos, cnt, (float*)d_out);
}

// Round 9
// 214.707 us; speedup vs baseline: 1.1819x; 1.1819x over previous
//
#include <hip/hip_runtime.h>
#include <math.h>

#define TEMP_INV (1.0f / 0.07f)
#define WEIGHT 0.5f
#define EPS 1e-8f
#define BB 64
#define TT 512
#define DD 512
#define RR 4   // rows per wave (plain compiler-scheduled; 16384 waves)

typedef float f32x4 __attribute__((ext_vector_type(4)));

__device__ inline float wave_sum(float v) {
    for (int o = 32; o >= 1; o >>= 1) v += __shfl_xor(v, o, 64);
    return v;
}
__device__ inline int wave_max_i(int v) {
    for (int o = 32; o >= 1; o >>= 1) v = max(v, __shfl_xor(v, o, 64));
    return v;
}
__device__ inline int wave_min_i(int v) {
    for (int o = 32; o >= 1; o >>= 1) v = min(v, __shfl_xor(v, o, 64));
    return v;
}

// One block (256 threads) per batch element b:
//  - argmax(mask[b,:]) with first-occurrence semantics
//  - normalized anchors a_anchor[b,:], v_anchor[b,:]
//  - pos[b] = dot(v_anchor_n, a_anchor_n)/TEMP
//  - zero the neg accumulators (ws is poisoned each call)
__global__ __launch_bounds__(256) void prep_kernel(
    const float* __restrict__ video, const float* __restrict__ audio,
    const int* __restrict__ mask,
    float* __restrict__ a_anchor, float* __restrict__ v_anchor,
    float* __restrict__ pos, float* __restrict__ neg, int* __restrict__ idx_out)
{
    const int b = blockIdx.x;
    const int tid = threadIdx.x;
    const int wid = tid >> 6, lane = tid & 63;
    __shared__ int sh_i[4];
    __shared__ float sh_f[4][3];
    __shared__ int s_idx;
    __shared__ float s_inva, s_invv;

    // ---- argmax (first max) over mask[b, 0..T) ----
    int m0 = mask[b * TT + tid];
    int m1 = mask[b * TT + tid + 256];
    int vmax = wave_max_i(max(m0, m1));
    if (lane == 0) sh_i[wid] = vmax;
    __syncthreads();
    if (tid == 0) {
        int r = sh_i[0];
        for (int i = 1; i < 4; i++) r = max(r, sh_i[i]);
        sh_i[0] = r;
    }
    __syncthreads();
    vmax = sh_i[0];
    __syncthreads();
    int cand = (m0 == vmax) ? tid : 0x7fffffff;
    int cand1 = (m1 == vmax) ? (tid + 256) : 0x7fffffff;
    cand = min(cand, cand1);
    cand = wave_min_i(cand);
    if (lane == 0) sh_i[wid] = cand;
    __syncthreads();
    if (tid == 0) {
        int r = sh_i[0];
        for (int i = 1; i < 4; i++) r = min(r, sh_i[i]);
        s_idx = r;
    }
    __syncthreads();
    const int idx = s_idx;

    // ---- anchor rows: sumsq(audio), sumsq(video), dot(audio,video) ----
    const float* arow = audio + ((size_t)(b * TT + idx)) * DD;
    const float* vrow = video + ((size_t)(b * TT + idx)) * DD;
    float a0 = arow[tid], a1 = arow[tid + 256];
    float v0 = vrow[tid], v1 = vrow[tid + 256];
    float ssa = a0 * a0 + a1 * a1;
    float ssv = v0 * v0 + v1 * v1;
    float dav = a0 * v0 + a1 * v1;
    ssa = wave_sum(ssa);
    ssv = wave_sum(ssv);
    dav = wave_sum(dav);
    if (lane == 0) { sh_f[wid][0] = ssa; sh_f[wid][1] = ssv; sh_f[wid][2] = dav; }
    __syncthreads();
    if (tid == 0) {
        float ra = 0.f, rv = 0.f, rd = 0.f;
        for (int i = 0; i < 4; i++) { ra += sh_f[i][0]; rv += sh_f[i][1]; rd += sh_f[i][2]; }
        float inva = 1.0f / fmaxf(sqrtf(ra), EPS);
        float invv = 1.0f / fmaxf(sqrtf(rv), EPS);
        s_inva = inva; s_invv = invv;
        pos[b] = rd * inva * invv * TEMP_INV;
        neg[b] = 0.0f;
        neg[BB + b] = 0.0f;
        idx_out[b] = idx;
    }
    __syncthreads();
    const float inva = s_inva, invv = s_invv;
    a_anchor[b * DD + tid] = a0 * inva;
    a_anchor[b * DD + tid + 256] = a1 * inva;
    v_anchor[b * DD + tid] = v0 * invv;
    v_anchor[b * DD + tid + 256] = v1 * invv;
}

// grid (T/16, B, 2); 256-thread blocks, one wave per RR=4 consecutive rows.
// R2's compiler-scheduled body (NEVER force drains: sched_barrier / LDS-DMA /
// asm vmcnt(0) / fused-ticket-fence all landed at 100-147 us vs 61.8).
// RR=4 doubles wave count vs R2 (16384 waves = 2x device capacity) while the
// compiler sustains its usual 2-4 in-flight loads per wave. Rows are
// read-once -> nontemporal loads (no L1/L2 allocation); anchors stay cached.
__global__ __launch_bounds__(256) void sims_kernel(
    const float* __restrict__ video, const float* __restrict__ audio,
    const float* __restrict__ a_anchor, const float* __restrict__ v_anchor,
    const int* __restrict__ idx_arr, float* __restrict__ neg)
{
    const int b = blockIdx.y;
    const int dir = blockIdx.z;
    const int wid = threadIdx.x >> 6, lane = threadIdx.x & 63;
    const int t0 = blockIdx.x * (4 * RR) + wid * RR;

    const float* base = (dir == 0 ? video : audio) + (size_t)b * TT * DD;
    const float* anc = (dir == 0 ? a_anchor : v_anchor) + b * DD;

    // anchor first: L2-hit, completes early
    f32x4 c0 = *(const f32x4*)(anc + lane * 4);
    f32x4 c1 = *(const f32x4*)(anc + 256 + lane * 4);

    f32x4 r0[RR], r1[RR];
#pragma unroll
    for (int r = 0; r < RR; r++) {
        const float* row = base + (size_t)(t0 + r) * DD;
        r0[r] = __builtin_nontemporal_load((const f32x4*)(row + lane * 4));
        r1[r] = __builtin_nontemporal_load((const f32x4*)(row + 256 + lane * 4));
    }

    float dot[RR], nrm[RR];
#pragma unroll
    for (int r = 0; r < RR; r++) {
        dot[r] = r0[r].x * c0.x + r0[r].y * c0.y + r0[r].z * c0.z + r0[r].w * c0.w
               + r1[r].x * c1.x + r1[r].y * c1.y + r1[r].z * c1.z + r1[r].w * c1.w;
        nrm[r] = r0[r].x * r0[r].x + r0[r].y * r0[r].y + r0[r].z * r0[r].z + r0[r].w * r0[r].w
               + r1[r].x * r1[r].x + r1[r].y * r1[r].y + r1[r].z * r1[r].z + r1[r].w * r1[r].w;
    }

    // batched butterfly: 6 levels, 2*RR independent shfl-adds per level
#pragma unroll
    for (int o = 32; o >= 1; o >>= 1) {
#pragma unroll
        for (int r = 0; r < RR; r++) {
            dot[r] += __shfl_xor(dot[r], o, 64);
            nrm[r] += __shfl_xor(nrm[r], o, 64);
        }
    }

    if (lane == 0) {
        const int idx = idx_arr[b];
        float local = 0.0f;
#pragma unroll
        for (int r = 0; r < RR; r++) {
            const int t = t0 + r;
            float sim = dot[r] / fmaxf(sqrtf(nrm[r]), EPS) * TEMP_INV;
            local += (t == idx) ? 0.0f : expf(sim);
        }
        atomicAdd(&neg[dir * BB + b], local);
    }
}

__global__ void finalize_kernel(const float* __restrict__ pos,
                                const float* __restrict__ neg,
                                float* __restrict__ out)
{
    const int b = threadIdx.x;  // 64 threads, one wave
    float term = WEIGHT * (logf(neg[b]) + logf(neg[BB + b])) - pos[b];
    term = wave_sum(term);
    if (b == 0) out[0] = term / (float)BB;
}

extern "C" void kernel_launch(void* const* d_in, const int* in_sizes, int n_in,
                              void* d_out, int out_size, void* d_ws, size_t ws_size,
                              hipStream_t stream)
{
    const float* video = (const float*)d_in[0];
    const float* audio = (const float*)d_in[1];
    const int* mask = (const int*)d_in[2];

    float* ws = (float*)d_ws;
    float* a_anchor = ws;                 // B*D
    float* v_anchor = ws + BB * DD;       // B*D
    float* pos = ws + 2 * BB * DD;        // B
    float* neg = pos + BB;                // 2*B
    int* idx = (int*)(neg + 2 * BB);      // B

    prep_kernel<<<BB, 256, 0, stream>>>(video, audio, mask, a_anchor, v_anchor, pos, neg, idx);
    dim3 grid(TT / (4 * RR), BB, 2);
    sims_kernel<<<grid, 256, 0, stream>>>(video, audio, a_anchor, v_anchor, idx, neg);
    finalize_kernel<<<1, 64, 0, stream>>>(pos, neg, (float*)d_out);
}

// Round 10
// 158.307 us; speedup vs baseline: 1.6030x; 1.3563x over previous
//
#include <hip/hip_runtime.h>
#include <math.h>

#define TEMP_INV (1.0f / 0.07f)
#define WEIGHT 0.5f
#define EPS 1e-8f
#define BB 64
#define TT 512
#define DD 512
#define RR 4                 // rows per chunk
#define NC 4                 // chunks per wave -> 16 rows/wave
#define ROWS_PER_WAVE (RR * NC)

typedef float f32x4 __attribute__((ext_vector_type(4)));

__device__ inline float wave_sum(float v) {
    for (int o = 32; o >= 1; o >>= 1) v += __shfl_xor(v, o, 64);
    return v;
}
__device__ inline int wave_max_i(int v) {
    for (int o = 32; o >= 1; o >>= 1) v = max(v, __shfl_xor(v, o, 64));
    return v;
}
__device__ inline int wave_min_i(int v) {
    for (int o = 32; o >= 1; o >>= 1) v = min(v, __shfl_xor(v, o, 64));
    return v;
}

// One block (256 threads) per batch element b (unchanged, proven).
__global__ __launch_bounds__(256) void prep_kernel(
    const float* __restrict__ video, const float* __restrict__ audio,
    const int* __restrict__ mask,
    float* __restrict__ a_anchor, float* __restrict__ v_anchor,
    float* __restrict__ pos, float* __restrict__ neg, int* __restrict__ idx_out)
{
    const int b = blockIdx.x;
    const int tid = threadIdx.x;
    const int wid = tid >> 6, lane = tid & 63;
    __shared__ int sh_i[4];
    __shared__ float sh_f[4][3];
    __shared__ int s_idx;
    __shared__ float s_inva, s_invv;

    int m0 = mask[b * TT + tid];
    int m1 = mask[b * TT + tid + 256];
    int vmax = wave_max_i(max(m0, m1));
    if (lane == 0) sh_i[wid] = vmax;
    __syncthreads();
    if (tid == 0) {
        int r = sh_i[0];
        for (int i = 1; i < 4; i++) r = max(r, sh_i[i]);
        sh_i[0] = r;
    }
    __syncthreads();
    vmax = sh_i[0];
    __syncthreads();
    int cand = (m0 == vmax) ? tid : 0x7fffffff;
    int cand1 = (m1 == vmax) ? (tid + 256) : 0x7fffffff;
    cand = min(cand, cand1);
    cand = wave_min_i(cand);
    if (lane == 0) sh_i[wid] = cand;
    __syncthreads();
    if (tid == 0) {
        int r = sh_i[0];
        for (int i = 1; i < 4; i++) r = min(r, sh_i[i]);
        s_idx = r;
    }
    __syncthreads();
    const int idx = s_idx;

    const float* arow = audio + ((size_t)(b * TT + idx)) * DD;
    const float* vrow = video + ((size_t)(b * TT + idx)) * DD;
    float a0 = arow[tid], a1 = arow[tid + 256];
    float v0 = vrow[tid], v1 = vrow[tid + 256];
    float ssa = a0 * a0 + a1 * a1;
    float ssv = v0 * v0 + v1 * v1;
    float dav = a0 * v0 + a1 * v1;
    ssa = wave_sum(ssa);
    ssv = wave_sum(ssv);
    dav = wave_sum(dav);
    if (lane == 0) { sh_f[wid][0] = ssa; sh_f[wid][1] = ssv; sh_f[wid][2] = dav; }
    __syncthreads();
    if (tid == 0) {
        float ra = 0.f, rv = 0.f, rd = 0.f;
        for (int i = 0; i < 4; i++) { ra += sh_f[i][0]; rv += sh_f[i][1]; rd += sh_f[i][2]; }
        float inva = 1.0f / fmaxf(sqrtf(ra), EPS);
        float invv = 1.0f / fmaxf(sqrtf(rv), EPS);
        s_inva = inva; s_invv = invv;
        pos[b] = rd * inva * invv * TEMP_INV;
        neg[b] = 0.0f;
        neg[BB + b] = 0.0f;
        idx_out[b] = idx;
    }
    __syncthreads();
    const float inva = s_inva, invv = s_invv;
    a_anchor[b * DD + tid] = a0 * inva;
    a_anchor[b * DD + tid + 256] = a1 * inva;
    v_anchor[b * DD + tid] = v0 * invv;
    v_anchor[b * DD + tid + 256] = v1 * invv;
}

#define LOADC(B0, B1, CH)                                                   \
    _Pragma("unroll")                                                       \
    for (int r = 0; r < RR; r++) {                                          \
        const float* row_ = base + (size_t)(t0 + (CH) * RR + r) * DD;       \
        B0[r] = *(const f32x4*)(row_ + lane * 4);                           \
        B1[r] = *(const f32x4*)(row_ + 256 + lane * 4);                     \
    }

#define COMPC(B0, B1, CH)                                                   \
    _Pragma("unroll")                                                       \
    for (int r = 0; r < RR; r++) {                                          \
        const int k_ = (CH) * RR + r;                                       \
        dot[k_] = B0[r].x * c0.x + B0[r].y * c0.y + B0[r].z * c0.z          \
                + B0[r].w * c0.w + B1[r].x * c1.x + B1[r].y * c1.y          \
                + B1[r].z * c1.z + B1[r].w * c1.w;                          \
        nrm[k_] = B0[r].x * B0[r].x + B0[r].y * B0[r].y + B0[r].z * B0[r].z \
                + B0[r].w * B0[r].w + B1[r].x * B1[r].x + B1[r].y * B1[r].y \
                + B1[r].z * B1[r].z + B1[r].w * B1[r].w;                    \
    }

// grid (T/64, B, 2) = 1024 blocks, 4096 waves (all device-resident).
// Software-pipelined: ping-pong chunk buffers, loads of chunk i+1 sit
// BEFORE compute of chunk i in program order (compiler's fine-grained
// vmcnt keeps one 4KB batch in flight through every compute phase).
// All butterflies deferred to one batched 32-value end-reduction — no
// per-chunk serial tail. No forced drains anywhere (R3/R4/R6/R8 lesson).
__global__ __launch_bounds__(256) void sims_kernel(
    const float* __restrict__ video, const float* __restrict__ audio,
    const float* __restrict__ a_anchor, const float* __restrict__ v_anchor,
    const int* __restrict__ idx_arr, float* __restrict__ neg)
{
    const int b = blockIdx.y;
    const int dir = blockIdx.z;
    const int wid = threadIdx.x >> 6, lane = threadIdx.x & 63;
    const int t0 = blockIdx.x * (4 * ROWS_PER_WAVE) + wid * ROWS_PER_WAVE;

    const float* base = (dir == 0 ? video : audio) + (size_t)b * TT * DD;
    const float* anc = (dir == 0 ? a_anchor : v_anchor) + b * DD;

    f32x4 c0 = *(const f32x4*)(anc + lane * 4);
    f32x4 c1 = *(const f32x4*)(anc + 256 + lane * 4);

    f32x4 pa0[RR], pa1[RR], pb0[RR], pb1[RR];
    float dot[ROWS_PER_WAVE], nrm[ROWS_PER_WAVE];

    LOADC(pa0, pa1, 0)          // chunk 0 in flight
    LOADC(pb0, pb1, 1)          // chunk 1 in flight
    COMPC(pa0, pa1, 0)          // consume 0 (waits vmcnt for batch 0 only)
    LOADC(pa0, pa1, 2)          // chunk 2 in flight
    COMPC(pb0, pb1, 1)          // consume 1
    LOADC(pb0, pb1, 3)          // chunk 3 in flight
    COMPC(pa0, pa1, 2)          // consume 2
    COMPC(pb0, pb1, 3)          // consume 3

    // one batched butterfly: 6 levels x 32 independent shfl-adds
#pragma unroll
    for (int o = 32; o >= 1; o >>= 1) {
#pragma unroll
        for (int k = 0; k < ROWS_PER_WAVE; k++) {
            dot[k] += __shfl_xor(dot[k], o, 64);
            nrm[k] += __shfl_xor(nrm[k], o, 64);
        }
    }

    if (lane == 0) {
        const int idx = idx_arr[b];
        float local = 0.0f;
#pragma unroll
        for (int k = 0; k < ROWS_PER_WAVE; k++) {
            const int t = t0 + k;
            float sim = dot[k] / fmaxf(sqrtf(nrm[k]), EPS) * TEMP_INV;
            local += (t == idx) ? 0.0f : expf(sim);
        }
        atomicAdd(&neg[dir * BB + b], local);
    }
}

__global__ void finalize_kernel(const float* __restrict__ pos,
                                const float* __restrict__ neg,
                                float* __restrict__ out)
{
    const int b = threadIdx.x;  // 64 threads, one wave
    float term = WEIGHT * (logf(neg[b]) + logf(neg[BB + b])) - pos[b];
    term = wave_sum(term);
    if (b == 0) out[0] = term / (float)BB;
}

extern "C" void kernel_launch(void* const* d_in, const int* in_sizes, int n_in,
                              void* d_out, int out_size, void* d_ws, size_t ws_size,
                              hipStream_t stream)
{
    const float* video = (const float*)d_in[0];
    const float* audio = (const float*)d_in[1];
    const int* mask = (const int*)d_in[2];

    float* ws = (float*)d_ws;
    float* a_anchor = ws;                 // B*D
    float* v_anchor = ws + BB * DD;       // B*D
    float* pos = ws + 2 * BB * DD;        // B
    float* neg = pos + BB;                // 2*B
    int* idx = (int*)(neg + 2 * BB);      // B

    prep_kernel<<<BB, 256, 0, stream>>>(video, audio, mask, a_anchor, v_anchor, pos, neg, idx);
    dim3 grid(TT / (4 * ROWS_PER_WAVE), BB, 2);
    sims_kernel<<<grid, 256, 0, stream>>>(video, audio, a_anchor, v_anchor, idx, neg);
    finalize_kernel<<<1, 64, 0, stream>>>(pos, neg, (float*)d_out);
}